// Round 4
// baseline (658.372 us; speedup 1.0000x reference)
//
#include <hip/hip_runtime.h>
#include <stdint.h>

#define RDIM 14
#define CDIM 64
#define NFRAMES 4

// Persistent-block version of the round-1 kernel (best measured: ~151us).
// 1024 blocks (4/CU) each process ~8 tiles of 256 rows. LDS is double-
// buffered: tile t+1's DMA is issued BEFORE computing tile t, and the single
// __syncthreads per tile (vmcnt drain + barrier) lands after a full compute
// phase -> staging latency hidden, weight cache amortized 8x.
// Compute body is exactly round-1's (7x ds_read_b64 + two scalar fmaf
// chains): round-3's ds_read_b128 pairs + asm v_pk_fma regressed ~10%.
constexpr int BLOCK = 256;
constexpr int TILE_ROWS = 256;
constexpr int ROWS_PER_WAVE = 64;
constexpr int X_TILE_FLOATS = TILE_ROWS * RDIM;            // 3584
constexpr int X_TILE_BYTES  = X_TILE_FLOATS * 4;           // 14336
constexpr int CHUNK_BYTES   = 64 * 16;                     // 1024 per wave-issue
constexpr int N_CHUNKS      = X_TILE_BYTES / CHUNK_BYTES;  // 14
constexpr int PERSISTENT_BLOCKS = 1024;                    // 4 blocks/CU x 256 CU

typedef const __attribute__((address_space(1))) uint32_t* gptr_t;
typedef __attribute__((address_space(3))) uint32_t* lptr_t;

__global__ __launch_bounds__(BLOCK, 4) void frame_proj_kernel(
    const float* __restrict__ X,      // (batch, 14)
    const int* __restrict__ ids,      // (batch,)
    const float* __restrict__ W,      // (4, 64, 14)
    const float* __restrict__ B,      // (4, 64)
    float* __restrict__ out,          // (batch, 64)
    int batch)
{
    __shared__ float xs[2][X_TILE_FLOATS];   // 2 x 14336 B

    const int tid  = threadIdx.x;
    const int lane = tid & 63;
    const int wid  = __builtin_amdgcn_readfirstlane(tid >> 6);
    const int waveRow0 = wid * ROWS_PER_WAVE;     // within tile

    const int ntiles = (batch + TILE_ROWS - 1) / TILE_ROWS;

    auto stage = [&](int tile, int buf) {
        const int tb = tile * TILE_ROWS;
        const int trows = min(TILE_ROWS, batch - tb);
        if (trows == TILE_ROWS) {
            const char* gsrc = (const char*)(X + (size_t)tb * RDIM);
            for (int c = wid; c < N_CHUNKS; c += 4) {   // 3-4 issues per wave
                __builtin_amdgcn_global_load_lds(
                    (gptr_t)(const void*)(gsrc + c * CHUNK_BYTES + lane * 16),
                    (lptr_t)(void*)((char*)xs[buf] + c * CHUNK_BYTES),
                    16, 0, 0);
            }
        } else {
            for (int i = tid; i < trows * RDIM; i += BLOCK)
                xs[buf][i] = X[(size_t)tb * RDIM + i];
        }
    };

    auto load_ids = [&](int tile) -> int {
        const int g = tile * TILE_ROWS + waveRow0 + lane;
        return (g < batch) ? ids[g] : 0;
    };

    int t = blockIdx.x;
    if (t >= ntiles) return;

    // ---- prologue: get tile t's DMA in flight before anything else ----
    stage(t, 0);
    int idv = load_ids(t);

    // ---- per-lane weight cache (lane = output column), pinned in VGPRs ----
    // Loaded ONCE per persistent block (amortized over ~8 tiles / 2048 rows).
    float w[NFRAMES][RDIM];
    float bb[NFRAMES];
#pragma unroll
    for (int e = 0; e < NFRAMES; ++e) {
        const float2* wr = (const float2*)(W + (size_t)(e * CDIM + lane) * RDIM);
#pragma unroll
        for (int k = 0; k < 7; ++k) {
            float2 v = wr[k];
            w[e][2 * k]     = v.x;
            w[e][2 * k + 1] = v.y;
        }
        bb[e] = B[e * CDIM + lane];
    }
    // Pin: without this the compiler sinks weight loads into the row loop
    // (round-0 kernel: VGPR_Count=32, the cache never existed in registers).
#pragma unroll
    for (int e = 0; e < NFRAMES; ++e) {
#pragma unroll
        for (int k = 0; k < RDIM; ++k) asm volatile("" : "+v"(w[e][k]));
        asm volatile("" : "+v"(bb[e]));
    }

    __syncthreads();   // drains tile t's DMA + barrier

    int cur = 0;
    while (true) {
        // ---- issue next tile's staging before computing current ----
        const int tn = t + gridDim.x;
        const bool havenext = (tn < ntiles);
        if (havenext) stage(tn, cur ^ 1);
        const int idv_next = havenext ? load_ids(tn) : 0;

        // ---- compute tile t from xs[cur] (round-1 body, verbatim) ----
        const int tb = t * TILE_ROWS;
        const int nrows = min(ROWS_PER_WAVE, batch - tb - waveRow0);
        const float2* xr2 = (const float2*)(xs[cur]) + waveRow0 * (RDIM / 2);
        float* orow = out + (size_t)(tb + waveRow0) * CDIM + lane;

        for (int r = 0; r < nrows; ++r) {
            // Expert id: in-register, wave-uniform.
            const int id = __builtin_amdgcn_readlane(idv, r);

            // x row: 7x ds_read_b64, uniform address -> broadcast.
            float xv[RDIM];
#pragma unroll
            for (int k = 0; k < RDIM / 2; ++k) {
                float2 v = xr2[r * (RDIM / 2) + k];
                xv[2 * k]     = v.x;
                xv[2 * k + 1] = v.y;
            }

            auto dot = [&](const float (&wk)[RDIM], float bias) {
                float a0 = bias, a1 = 0.0f;   // two chains halve FMA latency
#pragma unroll
                for (int k = 0; k < RDIM; k += 2) {
                    a0 = fmaf(xv[k],     wk[k],     a0);
                    a1 = fmaf(xv[k + 1], wk[k + 1], a1);
                }
                return a0 + a1;
            };

            float acc;
            if (id == 0)      acc = dot(w[0], bb[0]);   // wave-uniform branch
            else if (id == 1) acc = dot(w[1], bb[1]);
            else if (id == 2) acc = dot(w[2], bb[2]);
            else              acc = dot(w[3], bb[3]);

            orow[(size_t)r * CDIM] = acc;   // 256B coalesced store per row
        }

        if (!havenext) break;
        __syncthreads();   // next tile's DMA (issued pre-compute) now drained
        t = tn;
        cur ^= 1;
        idv = idv_next;
    }
}

extern "C" void kernel_launch(void* const* d_in, const int* in_sizes, int n_in,
                              void* d_out, int out_size, void* d_ws, size_t ws_size,
                              hipStream_t stream) {
    const float* X   = (const float*)d_in[0];
    const int*   ids = (const int*)d_in[1];
    const float* W   = (const float*)d_in[2];
    const float* B   = (const float*)d_in[3];
    float* out = (float*)d_out;

    const int batch = in_sizes[1];  // frame_type_ids element count

    const int ntiles = (batch + TILE_ROWS - 1) / TILE_ROWS;
    const int grid = min(ntiles, PERSISTENT_BLOCKS);
    frame_proj_kernel<<<grid, BLOCK, 0, stream>>>(X, ids, W, B, out, batch);
}

// Round 5
// 606.394 us; speedup vs baseline: 1.0857x; 1.0857x over previous
//
#include <hip/hip_runtime.h>
#include <stdint.h>

#define RDIM 14
#define CDIM 64
#define NFRAMES 4

// Wave-independent register-staged version. Evidence so far (kernel-portion
// ledger): R1 plain LDS-stage = 151us; pad-swizzle (R2) = 209; b128 pairs +
// asm pk_fma (R3) = 166; persistent dbuf (R4) = 192 -- every elaboration of
// the LDS staging machinery lost. This version deletes that machinery:
// each wave's 64 rows of X = 3584B = 14 VGPRs/lane, loaded coalesced and
// broadcast per-row via v_readlane (row loop fully unrolled -> all register
// and lane indices compile-time). No LDS, no __syncthreads, no DMA; a wave
// is one VMEM burst + pure VALU/store stream. Issue floor ~56us/SIMD vs
// 105us memory floor -> write-stream-bound.
constexpr int BLOCK = 256;
constexpr int WAVES_PER_BLOCK = BLOCK / 64;
constexpr int ROWS_PER_WAVE = 64;
constexpr int XREGS = ROWS_PER_WAVE * RDIM / 64;   // 14

__global__ __launch_bounds__(BLOCK, 4) void frame_proj_kernel(
    const float* __restrict__ X,      // (batch, 14)
    const int* __restrict__ ids,      // (batch,)
    const float* __restrict__ W,      // (4, 64, 14)
    const float* __restrict__ B,      // (4, 64)
    float* __restrict__ out,          // (batch, 64)
    int batch)
{
    const int lane = threadIdx.x & 63;
    const int wid  = __builtin_amdgcn_readfirstlane(threadIdx.x >> 6);
    const int gwid = blockIdx.x * WAVES_PER_BLOCK + wid;
    const int row0 = gwid * ROWS_PER_WAVE;
    if (row0 >= batch) return;

    // ---- per-lane weight cache (lane = output column), pinned in VGPRs ----
    float w[NFRAMES][RDIM];
    float bb[NFRAMES];
#pragma unroll
    for (int e = 0; e < NFRAMES; ++e) {
        const float2* wr = (const float2*)(W + (size_t)(e * CDIM + lane) * RDIM);
#pragma unroll
        for (int k = 0; k < 7; ++k) {
            float2 v = wr[k];
            w[e][2 * k]     = v.x;
            w[e][2 * k + 1] = v.y;
        }
        bb[e] = B[e * CDIM + lane];
    }
    // Pin: without this the compiler sinks weight loads into the row loop
    // (round-0 kernel: VGPR_Count=32, the cache never existed in registers).
#pragma unroll
    for (int e = 0; e < NFRAMES; ++e) {
#pragma unroll
        for (int k = 0; k < RDIM; ++k) asm volatile("" : "+v"(w[e][k]));
        asm volatile("" : "+v"(bb[e]));
    }

    auto dot = [&](const float (&xs)[RDIM], const float (&wk)[RDIM], float bias) {
        float a0 = bias, a1 = 0.0f;   // two chains halve dependent-FMA latency
#pragma unroll
        for (int k = 0; k < RDIM; k += 2) {
            a0 = fmaf(xs[k],     wk[k],     a0);
            a1 = fmaf(xs[k + 1], wk[k + 1], a1);
        }
        return a0 + a1;
    };

    if (row0 + ROWS_PER_WAVE <= batch) {
        // ---- fast path: whole 64-row slab staged into registers ----
        const int idv = ids[row0 + lane];              // 256B coalesced
        const float* xbase = X + (size_t)row0 * RDIM;  // 3584B slab
        float xg[XREGS];
#pragma unroll
        for (int j = 0; j < XREGS; ++j)                // 14 coalesced dword loads
            xg[j] = xbase[j * 64 + lane];
#pragma unroll
        for (int j = 0; j < XREGS; ++j) asm volatile("" : "+v"(xg[j]));

        float* orow = out + (size_t)row0 * CDIM + lane;

#pragma unroll
        for (int r = 0; r < ROWS_PER_WAVE; ++r) {
            // Expert id: in-register, wave-uniform scalar.
            const int id = __builtin_amdgcn_readlane(idv, r);

            // Row r broadcast from the register slab: flat index r*14+k maps
            // to register (flat>>6), lane (flat&63) -- all compile-time.
            float xs[RDIM];
#pragma unroll
            for (int k = 0; k < RDIM; ++k) {
                const int flat = r * RDIM + k;
                xs[k] = __int_as_float(__builtin_amdgcn_readlane(
                            __float_as_int(xg[flat >> 6]), flat & 63));
            }

            float acc;
            if (id == 0)      acc = dot(xs, w[0], bb[0]);   // uniform branch
            else if (id == 1) acc = dot(xs, w[1], bb[1]);
            else if (id == 2) acc = dot(xs, w[2], bb[2]);
            else              acc = dot(xs, w[3], bb[3]);

            orow[(size_t)r * CDIM] = acc;   // 256B coalesced store per row
        }
    } else {
        // ---- tail path: per-row uniform loads (rare; correctness only) ----
        const int rend = batch - row0;
        for (int r = 0; r < rend; ++r) {
            const int id = __builtin_amdgcn_readfirstlane(ids[row0 + r]);
            const float2* xr2 = (const float2*)(X + (size_t)(row0 + r) * RDIM);
            float xs[RDIM];
#pragma unroll
            for (int k = 0; k < 7; ++k) {
                float2 v = xr2[k];
                xs[2 * k]     = v.x;
                xs[2 * k + 1] = v.y;
            }
            float acc;
            if (id == 0)      acc = dot(xs, w[0], bb[0]);
            else if (id == 1) acc = dot(xs, w[1], bb[1]);
            else if (id == 2) acc = dot(xs, w[2], bb[2]);
            else              acc = dot(xs, w[3], bb[3]);
            out[(size_t)(row0 + r) * CDIM + lane] = acc;
        }
    }
}

extern "C" void kernel_launch(void* const* d_in, const int* in_sizes, int n_in,
                              void* d_out, int out_size, void* d_ws, size_t ws_size,
                              hipStream_t stream) {
    const float* X   = (const float*)d_in[0];
    const int*   ids = (const int*)d_in[1];
    const float* W   = (const float*)d_in[2];
    const float* B   = (const float*)d_in[3];
    float* out = (float*)d_out;

    const int batch = in_sizes[1];  // frame_type_ids element count

    const int rows_per_block = ROWS_PER_WAVE * WAVES_PER_BLOCK;  // 256
    const int grid = (batch + rows_per_block - 1) / rows_per_block;
    frame_proj_kernel<<<grid, BLOCK, 0, stream>>>(X, ids, W, B, out, batch);
}